// Round 10
// baseline (504.279 us; speedup 1.0000x reference)
//
#include <hip/hip_runtime.h>

// QuestionFlowLayer: out[i] = concat(q[i], mean(q[0:i])) for q [1024, 64, 1024] f32.
//
// Round 9: grain-size probe at viable occupancy. Same barrier-free minimal-
// traffic serial column scan as R8 (146.0 us), but thread-per-FLOAT2-column:
//  - 32768 float2 columns -> 256 blocks x 128 threads = 2 waves/CU.
//  - Wave-access grain: 512 B (vs 256 B in R8, 1 KB in the failed 1-wave/CU
//    R6). Half the DRAM address streams per CU, double the burst length.
//  - Non-temporal on both streams (R8 isolated: +5%).
//  - In-flight per CU: 2 waves x 32 unroll x 512 B = 32 KB loads >> ~10 KB
//    needed to cover ~1000-cy HBM latency at ~10 B/cyc/CU.
typedef float f32x2 __attribute__((ext_vector_type(2)));

constexpr unsigned N_TURNS = 1024;
constexpr unsigned C2      = 32768;    // float2 columns (L*D/2)
constexpr unsigned OUT_ROW2 = 65536;   // float2 per output turn (2*L*D/2)

__global__ __launch_bounds__(128) void qflow_f2_scan(
        const f32x2* __restrict__ q, f32x2* __restrict__ out) {
    const unsigned c2 = blockIdx.x * 128u + threadIdx.x;  // [0, 32768)
    const unsigned l  = c2 >> 9;            // 512 float2 per l-row
    const unsigned d2 = c2 & 511u;          // float2 index within D

    const f32x2* qp = q + c2;                             // q[i] = qp[i*C2]
    f32x2* op = out + (size_t)l * 1024u + d2;             // v at op[i*OUT_ROW2]
                                                          // avg at +512
    f32x2 run = (f32x2)(0.0f);

    #pragma unroll 32
    for (unsigned i = 0; i < N_TURNS; ++i) {
        f32x2 v = __builtin_nontemporal_load(qp + (size_t)i * C2);
        const float inv = (i == 0) ? 0.0f : __builtin_amdgcn_rcpf((float)i);
        f32x2 a = run * inv;
        __builtin_nontemporal_store(v, op + (size_t)i * OUT_ROW2);
        __builtin_nontemporal_store(a, op + (size_t)i * OUT_ROW2 + 512u);
        run += v;
    }
}

extern "C" void kernel_launch(void* const* d_in, const int* in_sizes, int n_in,
                              void* d_out, int out_size, void* d_ws, size_t ws_size,
                              hipStream_t stream) {
    const f32x2* q = (const f32x2*)d_in[0];
    f32x2* out = (f32x2*)d_out;
    qflow_f2_scan<<<C2 / 128, 128, 0, stream>>>(q, out);
}

// Round 11
// 146.042 us; speedup vs baseline: 3.4530x; 3.4530x over previous
//
#include <hip/hip_runtime.h>

// QuestionFlowLayer: out[i] = concat(q[i], mean(q[0:i])) for q [1024, 64, 1024] f32.
//
// CHAMPION (R8, 146.0 us): one thread per scalar column, barrier-free serial
// scan, minimal traffic (268 MB read + 537 MB write), non-temporal on both
// touch-once streams. 5.51 TB/s effective = 87.5% of the 6.29 TB/s pure-copy
// ceiling on a 1R:2W three-stream pattern.
//
// Falsified alternatives (this session):
//  - two-pass chunked scan (R0: 236 us) — 2x read traffic
//  - __syncthreads block-scan (R2: 179 us) — vmcnt(0) drain per barrier
//  - raw-barrier block-scan, 8-16 waves/CU (R4: 168, R7: 166) — exchange tax
//  - wider grains at low occupancy (R6 f4: 186; R9 f2: 504 — codegen
//    serialized loads, VGPR=8, one load in flight)
//  - NT isolated on champion structure: 153.6 -> 146.0 (kept)
constexpr unsigned N_TURNS = 1024;
constexpr unsigned D_MOD   = 1024;
constexpr unsigned COLS    = 65536;                    // L*D scalar columns
constexpr unsigned ROW_STRIDE_OUT = 2u * D_MOD * 64u;  // floats per turn in out

__global__ __launch_bounds__(256) void qflow_scan_nt(
        const float* __restrict__ q, float* __restrict__ out) {
    unsigned c = blockIdx.x * 256u + threadIdx.x;   // column index [0, 65536)
    unsigned l = c >> 10;
    unsigned d = c & (D_MOD - 1u);

    const float* qp = q + c;                        // q[i][c] = qp[i*COLS]
    float* op = out + (size_t)l * (2u * D_MOD) + d; // out[i][l][d] = op[i*ROW]
    float run = 0.0f;
    #pragma unroll 32
    for (unsigned i = 0; i < N_TURNS; ++i) {
        float v = __builtin_nontemporal_load(qp + (size_t)i * COLS);
        float inv = (i == 0) ? 0.0f : __builtin_amdgcn_rcpf((float)i);
        float avg = run * inv;
        size_t ob = (size_t)i * ROW_STRIDE_OUT;
        __builtin_nontemporal_store(v, op + ob);
        __builtin_nontemporal_store(avg, op + ob + D_MOD);
        run += v;
    }
}

extern "C" void kernel_launch(void* const* d_in, const int* in_sizes, int n_in,
                              void* d_out, int out_size, void* d_ws, size_t ws_size,
                              hipStream_t stream) {
    const float* q = (const float*)d_in[0];
    float* out = (float*)d_out;
    qflow_scan_nt<<<COLS / 256, 256, 0, stream>>>(q, out);
}